// Round 1
// 427.160 us; speedup vs baseline: 1.0312x; 1.0312x over previous
//
#include <hip/hip_runtime.h>
#include <hip/hip_bf16.h>
#include <cstdint>
#include <cstddef>

#define C_IN 768
#define HW 120
#define WP 122
#define PIX (HW*HW)       // 14400
#define PPIX (WP*WP)      // 14884
#define S_CH 48
#define CCH 256           // channel chunk for transpose
#define LSTR 257          // LDS row stride (ushorts), 257 % 32 == 1 -> conflict-free

// ws layout (bytes)
#define OFF_POOL 0                    // 768*51*4 = 156672
#define OFF_HDD3 163840               // 48 floats
#define OFF_WT   262144               // 9*768*768*2 = 10616832
#define OFF_XTP  10878976             // 14884*768*2 = 22861824 ; end ~33.7MB

typedef __attribute__((ext_vector_type(8))) short short8;
typedef __attribute__((ext_vector_type(4))) float floatx4;
typedef __attribute__((ext_vector_type(4))) uint uint4v;

#define AS3(p) ((__attribute__((address_space(3))) uint*)(p))
#define AS1(p) ((const __attribute__((address_space(1))) uint*)(p))

__device__ inline ushort f2bf(float f) {
  union { float f; uint i; } v; v.f = f;
  uint r = v.i + 0x7FFF + ((v.i >> 16) & 1);   // round-to-nearest-even
  return (ushort)(r >> 16);
}

// PyTorch bicubic(3->5), a=-0.75, align_corners=False, border-replicate
__device__ __constant__ float M35[5][3] = {
  { 1.096f, -0.096f,  0.000f },
  { 0.612f,  0.460f, -0.072f },
  { 0.000f,  1.000f,  0.000f },
  {-0.072f,  0.460f,  0.612f },
  { 0.000f, -0.096f,  1.096f },
};

// ---------------- K0: zero-pad + transpose x (C,H,W) f32 -> xTp (122*122, C) bf16 ----
// Coalesced LDS-transpose version. grid (122 rows, 3 c-chunks), 256 thr.
__global__ __launch_bounds__(256) void k_pad_transpose(const float* __restrict__ x,
                                                       ushort* __restrict__ xTp) {
  int ph = blockIdx.x;          // padded row 0..121
  int c0 = blockIdx.y * CCH;    // 0, 256, 512
  int tid = threadIdx.x;
  ushort* rowbase = xTp + (size_t)ph * WP * C_IN;
  if (ph == 0 || ph == WP - 1) {
    uint4v z = {0, 0, 0, 0};
    for (int i = tid; i < WP * (CCH / 8); i += 256) {
      int w = i / (CCH / 8), j = i % (CCH / 8);
      *(uint4v*)&rowbase[(size_t)w * C_IN + c0 + j * 8] = z;
    }
    return;
  }
  int h = ph - 1;
  __shared__ ushort T[HW * LSTR];   // 120*257*2 = 61680 B
  int wave = tid >> 6, lane = tid & 63;
  // phase 1: wave reads 64 channels' rows, coalesced float2 (480 B/row)
  for (int k = 0; k < 64; k++) {
    int cl = wave * 64 + k;                       // local channel 0..255
    const float* src = x + (size_t)(c0 + cl) * PIX + h * HW;
    if (lane < 60) {
      float vx = src[2 * lane], vy = src[2 * lane + 1];
      T[(2 * lane) * LSTR + cl]     = f2bf(vx);
      T[(2 * lane + 1) * LSTR + cl] = f2bf(vy);
    }
  }
  __syncthreads();
  // phase 2: coalesced packed-uint writes, + zero pad columns w=0, w=121
  if (tid < 128) {
    *(uint*)&rowbase[c0 + 2 * tid] = 0;
    *(uint*)&rowbase[(size_t)(WP - 1) * C_IN + c0 + 2 * tid] = 0;
  }
  for (int idx = tid; idx < HW * (CCH / 2); idx += 256) {
    int w = idx >> 7, pr = idx & 127;
    uint a = T[w * LSTR + 2 * pr];
    uint b = T[w * LSTR + 2 * pr + 1];
    *(uint*)&rowbase[(size_t)(1 + w) * C_IN + c0 + 2 * pr] = a | (b << 16);
  }
}

// ---------------- K1: pooling per channel: a1, a3u (bicubic), a5 -> pooled[c][51] -----
__global__ __launch_bounds__(256) void k_pool(const float* __restrict__ x,
                                              float* __restrict__ pooled) {
  int c = blockIdx.x;
  int tid = threadIdx.x;
  __shared__ float fine[225];   // 15x15 grid of 8x8 block sums
  if (tid < 225) {
    int fr = tid / 15, fc = tid % 15;
    const float* base = x + (size_t)c * PIX + fr * 8 * HW + fc * 8;
    float s = 0.f;
#pragma unroll
    for (int r = 0; r < 8; r++) {
      floatx4 a = *(const floatx4*)(base + r * HW);
      floatx4 b = *(const floatx4*)(base + r * HW + 4);
#pragma unroll
      for (int j = 0; j < 4; j++) s += a[j] + b[j];
    }
    fine[tid] = s;
  }
  __syncthreads();
  if (tid == 0) {
    float a3[3][3], a5[5][5]; float tot = 0.f;
    for (int i = 0; i < 3; i++) for (int j = 0; j < 3; j++) {
      float s = 0.f;
      for (int a = 0; a < 5; a++) for (int b = 0; b < 5; b++) s += fine[(i*5+a)*15 + j*5+b];
      a3[i][j] = s / 1600.f; tot += s;
    }
    for (int i = 0; i < 5; i++) for (int j = 0; j < 5; j++) {
      float s = 0.f;
      for (int a = 0; a < 3; a++) for (int b = 0; b < 3; b++) s += fine[(i*3+a)*15 + j*3+b];
      a5[i][j] = s / 576.f;
    }
    float* out = pooled + c * 51;
    out[0] = tot / 14400.f;
    for (int p = 0; p < 5; p++) for (int q = 0; q < 5; q++) {
      float s = 0.f;
      for (int i = 0; i < 3; i++) for (int j = 0; j < 3; j++)
        s += M35[p][i] * M35[q][j] * a3[i][j];
      out[1 + p*5 + q] = s;       // a3u
      out[26 + p*5 + q] = a5[p][q];
    }
  }
}

// ---------------- K2: routing MLP -> hdd3[48] ----------------------------------------
__global__ __launch_bounds__(256) void k_route(const float* __restrict__ pooled,
                                               const float* __restrict__ w_pw1,
                                               const float* __restrict__ w_dw1,
                                               const float* __restrict__ w_dw2,
                                               float* __restrict__ hdd3) {
  int s = blockIdx.x;  // 0..47
  int tid = threadIdx.x;
  __shared__ float red[26][256];
  float acc[25]; float accw1 = 0.f;
#pragma unroll
  for (int q = 0; q < 25; q++) acc[q] = 0.f;
  for (int c = tid; c < C_IN; c += 256) {
    const float* pl = pooled + c * 51;
    float w1 = w_pw1[(size_t)s * 3 * C_IN + c];
    float w2 = w_pw1[(size_t)s * 3 * C_IN + C_IN + c];
    float w3 = w_pw1[(size_t)s * 3 * C_IN + 2 * C_IN + c];
    accw1 += w1 * pl[0];
#pragma unroll
    for (int q = 0; q < 25; q++) acc[q] += w2 * pl[1 + q] + w3 * pl[26 + q];
  }
#pragma unroll
  for (int q = 0; q < 25; q++) red[q][tid] = acc[q];
  red[25][tid] = accw1;
  for (int st = 128; st; st >>= 1) {
    __syncthreads();
    if (tid < st)
      for (int q = 0; q < 26; q++) red[q][tid] += red[q][tid + st];
  }
  __syncthreads();
  if (tid == 0) {
    float hdd[5][5];
    for (int p = 0; p < 5; p++) for (int q = 0; q < 5; q++) {
      float v = red[p*5+q][0] + red[25][0];
      hdd[p][q] = v > 0.f ? v : 0.f;
    }
    float wd1[9], wd2[9];
    for (int i = 0; i < 9; i++) { wd1[i] = w_dw1[s*9 + i]; wd2[i] = w_dw2[s*9 + i]; }
    float h2[3][3];
    for (int i = 0; i < 3; i++) for (int j = 0; j < 3; j++) {
      float v = 0.f;
      for (int u = 0; u < 3; u++) for (int vv = 0; vv < 3; vv++) v += wd1[u*3+vv] * hdd[i+u][j+vv];
      h2[i][j] = v > 0.f ? v : 0.f;
    }
    float v = 0.f;
    for (int u = 0; u < 3; u++) for (int vv = 0; vv < 3; vv++) v += wd2[u*3+vv] * h2[u][vv];
    hdd3[s] = v > 0.f ? v : 0.f;
  }
}

// ---------------- K3: gates + weight synthesis -> wt[tap][o][c] (bf16) ---------------
__global__ __launch_bounds__(256) void k_wt(const float* __restrict__ convs,
                                            const float* __restrict__ w_pw2,
                                            const float* __restrict__ hdd3,
                                            ushort* __restrict__ wt) {
  int o = blockIdx.x;  // 0..767
  int tid = threadIdx.x;
  __shared__ float g[3];
  if (tid < 3) {
    float v = 0.f;
    for (int s = 0; s < S_CH; s++)
      v += w_pw2[((size_t)tid * C_IN + o) * S_CH + s] * hdd3[s];
    g[tid] = 1.f / (1.f + __expf(-v));
  }
  __syncthreads();
  float g0 = g[0], g1 = g[1], g2 = g[2];
  const float* c0p = convs + (size_t)o * 6912;
  const float* c1p = convs + (size_t)(C_IN + o) * 6912;
  const float* c2p = convs + (size_t)(2 * C_IN + o) * 6912;
  for (int c = tid; c < C_IN; c += 256) {
#pragma unroll
    for (int tap = 0; tap < 9; tap++) {
      float v = g0 * c0p[c*9 + tap] + g1 * c1p[c*9 + tap] + g2 * c2p[c*9 + tap];
      wt[((size_t)tap * C_IN + o) * C_IN + c] = f2bf(v);
    }
  }
}

// ---------------- K4: main conv, MFMA 16x16x32 bf16 ----------------------------------
// Restructured vs previous round:
//  * chunk-outer / tap-inner: A staged as the 10x18-pixel UNION once per K-chunk
//    (6.4x less A staging traffic than per-tap restaging)
//  * double-buffered A and B, stage-next-then-compute, ONE barrier per iteration
//    (T3 minimum-2-phase: load latency hides under the 16-MFMA cluster)
//  * T2-style swizzle: linear global_load_lds dest + inverse-swizzled SOURCE address
//    + swizzled ds_read (slot ^= (row>>1)&3) -> 8-way bank conflict becomes 2-way (free)
//  * 1-D grid 720 with bijective XCD-chunked swizzle, n-tile-major so each XCD's
//    B panel (~1.8-3.5 MB) stays L2-resident
__global__ __launch_bounds__(256) void k_conv(const ushort* __restrict__ xTp,
                                              const ushort* __restrict__ wt,
                                              float* __restrict__ y) {
  // A union buffer: 180 pixels x 32 ch, padded to 768 slots of 16B; double-buffered
  __shared__ __align__(16) ushort Aun[2][768 * 8];   // 2 x 12288 B
  __shared__ __align__(16) ushort Bt[2][512 * 8];    // 2 x  8192 B   (total 40 KiB)
  int tid = threadIdx.x;
  int lane = tid & 63;
  int quad = lane >> 4, l15 = lane & 15;
  int wave = tid >> 6;
  int wave_m = wave >> 1, wave_n = wave & 1;

  // XCD-chunked bijective swizzle (720 % 8 == 0); wg = n_t*120 + m_t
  int bid = blockIdx.x;
  int wg = (bid & 7) * 90 + (bid >> 3);
  int n_t = wg / 120, m_t = wg - n_t * 120;
  int h0 = (m_t >> 3) << 3;    // 0..112 step 8
  int w0 = (m_t & 7) << 4;     // 0..112 step 16 (last tile: w 112..127, cols >=120 discarded)
  int n0 = n_t << 7;

  // ---- precomputed staging source offsets (ushort units) ----
  // A: slots t = r*256+tid ; slot t holds union pixel p=t>>2, source sub s=(t&3)^((p>>1)&3)
  size_t a_off[3];
#pragma unroll
  for (int r = 0; r < 3; r++) {
    int t = r * 256 + tid;
    int p = t >> 2; if (p > 179) p = 179;          // pad slots 720..767 -> harmless dup
    int sl = (t & 3) ^ ((p >> 1) & 3);
    int pr = p / 18, pc = p - pr * 18;             // union is 10 rows x 18 cols
    int pix = (h0 + pr) * WP + (w0 + pc);
    if (pix > PPIX - 1) pix = PPIX - 1;            // clamp: only affects discarded outputs
    a_off[r] = (size_t)pix * C_IN + sl * 8;
  }
  // B: slots t = r*256+tid ; row n=t>>2, source sub s=(t&3)^((n>>1)&3)
  size_t b_off[2];
#pragma unroll
  for (int r = 0; r < 2; r++) {
    int t = r * 256 + tid;
    int n = t >> 2;
    int sl = (t & 3) ^ ((n >> 1) & 3);
    b_off[r] = (size_t)(n0 + n) * C_IN + sl * 8;
  }
  // B read offsets (swizzled), constant per thread
  int b_rd[4];
#pragma unroll
  for (int nt = 0; nt < 4; nt++) {
    int n = wave_n * 64 + nt * 16 + l15;
    b_rd[nt] = n * 32 + ((quad ^ ((n >> 1) & 3)) << 3);
  }
  int amh = wave_m * 4;

  auto stageA = [&](int ncc, int na) {
#pragma unroll
    for (int r = 0; r < 3; r++)
      __builtin_amdgcn_global_load_lds(AS1(xTp + a_off[r] + ncc * 32),
                                       AS3(&Aun[na][(r * 256 + wave * 64) * 8]), 16, 0, 0);
  };
  auto stageB = [&](int ncc, int ntap, int nb) {
    const ushort* wb = wt + (size_t)ntap * C_IN * C_IN + ncc * 32;
#pragma unroll
    for (int r = 0; r < 2; r++)
      __builtin_amdgcn_global_load_lds(AS1(wb + b_off[r]),
                                       AS3(&Bt[nb][(r * 256 + wave * 64) * 8]), 16, 0, 0);
  };

  floatx4 acc[4][4];
#pragma unroll
  for (int i = 0; i < 4; i++)
#pragma unroll
    for (int j = 0; j < 4; j++) acc[i][j] = (floatx4){0.f, 0.f, 0.f, 0.f};

  // prologue: fill buffer 0 for (cc=0, tap=0)
  stageA(0, 0);
  stageB(0, 0, 0);
  __syncthreads();

  int pb = 0;
  for (int cc = 0; cc < 24; cc++) {
    int pa = cc & 1;
#pragma unroll
    for (int tap = 0; tap < 9; tap++) {
      const int kh = tap / 3, kw = tap % 3;        // compile-time (tap unrolled)
      // 1) issue next-iteration staging into the ALT buffers (overlaps with MFMA below)
      if (tap < 8) {
        stageB(cc, tap + 1, pb ^ 1);
      } else if (cc < 23) {
        stageB(cc + 1, 0, pb ^ 1);
        stageA(cc + 1, pa ^ 1);
      }
      // 2) fragments from CURRENT buffers (swizzled reads -> conflict-free)
      short8 bfr[4], af[4];
#pragma unroll
      for (int nt = 0; nt < 4; nt++) bfr[nt] = *(const short8*)&Bt[pb][b_rd[nt]];
#pragma unroll
      for (int mt = 0; mt < 4; mt++) {
        int p = (amh + mt + kh) * 18 + l15 + kw;
        int idx = p * 32 + ((quad ^ ((p >> 1) & 3)) << 3);
        af[mt] = *(const short8*)&Aun[pa][idx];
      }
      // 3) MFMA cluster
#pragma unroll
      for (int mt = 0; mt < 4; mt++)
#pragma unroll
        for (int nt = 0; nt < 4; nt++)
          acc[mt][nt] = __builtin_amdgcn_mfma_f32_16x16x32_bf16(af[mt], bfr[nt], acc[mt][nt], 0, 0, 0);
      // 4) single barrier: drains this wave's vmcnt (next bufs ready) + read-safety
      __syncthreads();
      pb ^= 1;
    }
  }

  // epilogue: D layout col(n)=lane&15, row(m)=quad*4+reg
  // tile row m = wave_m*64 + mt*16 + (quad*4+reg) -> h = h0+wave_m*4+mt, w = w0+quad*4+reg
#pragma unroll
  for (int mt = 0; mt < 4; mt++) {
    int h = h0 + wave_m * 4 + mt;
    int wbase = w0 + quad * 4;
    if (wbase < HW) {
#pragma unroll
      for (int nt = 0; nt < 4; nt++) {
        int n = n0 + wave_n * 64 + nt * 16 + l15;
        *(floatx4*)&y[(size_t)n * PIX + h * HW + wbase] = acc[mt][nt];
      }
    }
  }
}

extern "C" void kernel_launch(void* const* d_in, const int* in_sizes, int n_in,
                              void* d_out, int out_size, void* d_ws, size_t ws_size,
                              hipStream_t stream) {
  const float* x     = (const float*)d_in[0];
  const float* convs = (const float*)d_in[1];
  const float* w_pw1 = (const float*)d_in[2];
  const float* w_dw1 = (const float*)d_in[3];
  const float* w_dw2 = (const float*)d_in[4];
  const float* w_pw2 = (const float*)d_in[5];
  float* y = (float*)d_out;
  char* ws = (char*)d_ws;
  float*  pooled = (float*)(ws + OFF_POOL);
  float*  hdd3   = (float*)(ws + OFF_HDD3);
  ushort* wt     = (ushort*)(ws + OFF_WT);
  ushort* xTp    = (ushort*)(ws + OFF_XTP);

  hipLaunchKernelGGL(k_pad_transpose, dim3(122, 3), dim3(256), 0, stream, x, xTp);
  hipLaunchKernelGGL(k_pool,          dim3(768),    dim3(256), 0, stream, x, pooled);
  hipLaunchKernelGGL(k_route,         dim3(48),     dim3(256), 0, stream, pooled, w_pw1, w_dw1, w_dw2, hdd3);
  hipLaunchKernelGGL(k_wt,            dim3(768),    dim3(256), 0, stream, convs, w_pw2, hdd3, wt);
  hipLaunchKernelGGL(k_conv,          dim3(720),    dim3(256), 0, stream, xTp, wt, y);
}